// Round 3
// baseline (1865.412 us; speedup 1.0000x reference)
//
#include <hip/hip_runtime.h>
#include <hip/hip_bf16.h>
#include <hip/hip_cooperative_groups.h>

// Problem constants (DAG_61246233641129)
#define IN_SIZE 1024
#define N_NODES 4224
#define TOTAL   5248   // IN_SIZE + N_NODES
#define BATCH   512
#define OUTSZ   128
#define NB      128    // node block size
#define NBLK    33     // N_NODES / NB
#define NWG     256    // cooperative grid size
#define NSOLVER 16
#define NUPD    (NWG - NSOLVER)

namespace cg = cooperative_groups;

typedef __attribute__((ext_vector_type(8))) short short8;
typedef __attribute__((ext_vector_type(4))) float f32x4;

// fast tanh: tanh(x) = 1 - 2/(exp2(2x*log2e)+1)
__device__ __forceinline__ float fast_tanh(float x) {
  float e = __builtin_amdgcn_exp2f(x * 2.885390081777927f);
  return 1.0f - 2.0f * __builtin_amdgcn_rcpf(e + 1.0f);
}
__device__ __forceinline__ float fast_sigmoid(float x) {
  return __builtin_amdgcn_rcpf(1.0f + __builtin_amdgcn_exp2f(-x * 1.4426950408889634f));
}
__device__ __forceinline__ unsigned pack2(float a, float b) {
  __hip_bfloat162 h = __float22bfloat162_rn(float2{a, b});
  return *reinterpret_cast<unsigned*>(&h);
}
// load 8 contiguous f32, convert -> bf16x8 MFMA fragment
__device__ __forceinline__ short8 cvtA(const float* p) {
  float4 v0 = *(const float4*)p;
  float4 v1 = *(const float4*)(p + 4);
  union { uint4 u; short8 s; } c;
  c.u.x = pack2(v0.x, v0.y); c.u.y = pack2(v0.z, v0.w);
  c.u.z = pack2(v1.x, v1.y); c.u.w = pack2(v1.z, v1.w);
  return c.s;
}

// ---------------- cooperative mega-kernel ----------------
// Schedule per step k (one grid.sync each):
//   solver WGs 0..15 (32 batches each): fold src k-1 into col k (MFMA, direct
//     frags, bounce via Cl) + serial-solve block k + publish h (bf16 in Gt).
//   updater WGs 16..255: fold src k-1 into cols k+1..32 (disjoint from solver).
// Col c at solve time holds: init + sources 0..c-2 (updaters) + c-1 (solver).
__global__ void __launch_bounds__(256, 2)
mega(const float* __restrict__ W, const float* __restrict__ x,
     ushort* __restrict__ Gt, float* __restrict__ C, float* __restrict__ out) {
  cg::grid_group grid = cg::this_grid();
  __shared__ float Wt[NB][NB];   // 64 KB: diag weight block, transposed+swizzled
  __shared__ float Cl[NB][32];   // 16 KB: fold-output bounce (j-local x b-local)
  const int wg = blockIdx.x, t = threadIdx.x;
  const int w = t >> 6, l = t & 63, rl = l & 15, kh = l >> 4;

  // ---- phase 0: Gt[b][i] = bf16(x[b][i]) ----
  {
    int idx = wg * 256 + t;              // exactly 65536 threads, 8 elems each
    int b = idx >> 7, i8 = (idx & 127) * 8;
    const float* p = x + (size_t)b * IN_SIZE + i8;
    float4 v0 = *(const float4*)p, v1 = *(const float4*)(p + 4);
    uint4 o;
    o.x = pack2(v0.x, v0.y); o.y = pack2(v0.z, v0.w);
    o.z = pack2(v1.x, v1.y); o.w = pack2(v1.z, v1.w);
    *(uint4*)(Gt + (size_t)b * TOTAL + i8) = o;
  }
  grid.sync();

  // ---- phase 1: init C = W[:, :IN] . x^T  (264 tiles of 128j x 64b, K=1024) ----
  for (int tile = wg; tile < NBLK * 8; tile += NWG) {
    int col = tile >> 3, b0 = (tile & 7) * 64;
    int jw = col * NB + w * 32;
    f32x4 acc[2][4];
#pragma unroll
    for (int m = 0; m < 2; m++)
#pragma unroll
      for (int n = 0; n < 4; n++) acc[m][n] = f32x4{0.f, 0.f, 0.f, 0.f};
    const float* pa0 = W + (size_t)(jw + rl) * TOTAL + kh * 8;
    const float* pa1 = pa0 + (size_t)16 * TOTAL;
    const ushort* pb[4];
#pragma unroll
    for (int n = 0; n < 4; n++)
      pb[n] = Gt + (size_t)(b0 + n * 16 + rl) * TOTAL + kh * 8;
    for (int it = 0; it < 32; ++it) {
      short8 a0 = cvtA(pa0 + it * 32);
      short8 a1 = cvtA(pa1 + it * 32);
#pragma unroll
      for (int n = 0; n < 4; n++) {
        short8 bb = *(const short8*)(pb[n] + it * 32);
        acc[0][n] = __builtin_amdgcn_mfma_f32_16x16x32_bf16(a0, bb, acc[0][n], 0, 0, 0);
        acc[1][n] = __builtin_amdgcn_mfma_f32_16x16x32_bf16(a1, bb, acc[1][n], 0, 0, 0);
      }
    }
#pragma unroll
    for (int m = 0; m < 2; m++)
#pragma unroll
      for (int n = 0; n < 4; n++) {
        float* cp = C + (size_t)(jw + m * 16 + kh * 4) * BATCH + b0 + n * 16 + rl;
#pragma unroll
        for (int q = 0; q < 4; q++) cp[(size_t)q * BATCH] = acc[m][n][q];
      }
  }
  grid.sync();

  // ---- pipeline ----
  for (int k = 0; k < NBLK; ++k) {
    if (wg < NSOLVER) {
      const int b0 = wg * 32;
      const int j0 = k * NB;
      { // stage diag block Wt[i][swz(j)] = W[j0+j][IN+j0+i]
        int j = t & 127, half = t >> 7;
        int pj = j ^ (((j >> 5) & 3) << 2);
        const float* wr = W + (size_t)(j0 + j) * TOTAL + IN_SIZE + j0 + half * 64;
#pragma unroll
        for (int q = 0; q < 64; q += 4) {
          float4 v = *(const float4*)(wr + q);
          int i = half * 64 + q;
          Wt[i + 0][pj] = v.x; Wt[i + 1][pj] = v.y;
          Wt[i + 2][pj] = v.z; Wt[i + 3][pj] = v.w;
        }
      }
      if (k > 0) { // fold src k-1 into col k for own 32 batches (direct frags)
        int jw = j0 + w * 32;
        int kb = IN_SIZE + (k - 1) * NB;
        f32x4 a2[2][2];
#pragma unroll
        for (int m = 0; m < 2; m++)
#pragma unroll
          for (int n = 0; n < 2; n++) a2[m][n] = f32x4{0.f, 0.f, 0.f, 0.f};
        const float* pa0 = W + (size_t)(jw + rl) * TOTAL + kb + kh * 8;
        const float* pa1 = pa0 + (size_t)16 * TOTAL;
        const ushort* pb0 = Gt + (size_t)(b0 + rl) * TOTAL + kb + kh * 8;
        const ushort* pb1 = pb0 + (size_t)16 * TOTAL;
#pragma unroll
        for (int it = 0; it < 4; ++it) {
          short8 a0 = cvtA(pa0 + it * 32);
          short8 a1 = cvtA(pa1 + it * 32);
          short8 bb0 = *(const short8*)(pb0 + it * 32);
          short8 bb1 = *(const short8*)(pb1 + it * 32);
          a2[0][0] = __builtin_amdgcn_mfma_f32_16x16x32_bf16(a0, bb0, a2[0][0], 0, 0, 0);
          a2[0][1] = __builtin_amdgcn_mfma_f32_16x16x32_bf16(a0, bb1, a2[0][1], 0, 0, 0);
          a2[1][0] = __builtin_amdgcn_mfma_f32_16x16x32_bf16(a1, bb0, a2[1][0], 0, 0, 0);
          a2[1][1] = __builtin_amdgcn_mfma_f32_16x16x32_bf16(a1, bb1, a2[1][1], 0, 0, 0);
        }
#pragma unroll
        for (int m = 0; m < 2; m++)
#pragma unroll
          for (int n = 0; n < 2; n++)
#pragma unroll
            for (int q = 0; q < 4; q++)
              Cl[w * 32 + m * 16 + kh * 4 + q][n * 16 + rl] = a2[m][n][q];
      }
      __syncthreads();

      // serial solve: 8 lanes per batch, lane li owns nodes [16li,16li+16)
      int li = t & 7, g = t >> 3, b = b0 + g;
      float acc[16], hown[16];
      {
        const float* cb = C + (size_t)(j0 + li * 16) * BATCH + b;
#pragma unroll
        for (int m = 0; m < 16; m++) {
          float v = cb[(size_t)m * BATCH];
          if (k > 0) v += Cl[li * 16 + m][g];
          acc[m] = v;
        }
      }
      for (int r = 0; r < 8; r++) {
#pragma unroll
        for (int jj = 0; jj < 16; jj++) {
          int i = r * 16 + jj;
          float s = __shfl(acc[jj], r, 8);
          float h = fast_tanh(s);
          if (li == r) hown[jj] = h;
          const float* wrow = &Wt[i][0];
#pragma unroll
          for (int c = 0; c < 4; c++) {
            int col = li * 16 + c * 4;
            int pc = col ^ (((col >> 5) & 3) << 2);
            float4 wv = *(const float4*)(wrow + pc);
            acc[c * 4 + 0] += h * wv.x;
            acc[c * 4 + 1] += h * wv.y;
            acc[c * 4 + 2] += h * wv.z;
            acc[c * 4 + 3] += h * wv.w;
          }
        }
      }
      if (k < NBLK - 1) { // publish h (bf16)
        ushort* gp = Gt + (size_t)b * TOTAL + IN_SIZE + j0 + li * 16;
        uint4 o0, o1;
        o0.x = pack2(hown[0],  hown[1]);  o0.y = pack2(hown[2],  hown[3]);
        o0.z = pack2(hown[4],  hown[5]);  o0.w = pack2(hown[6],  hown[7]);
        o1.x = pack2(hown[8],  hown[9]);  o1.y = pack2(hown[10], hown[11]);
        o1.z = pack2(hown[12], hown[13]); o1.w = pack2(hown[14], hown[15]);
        ((uint4*)gp)[0] = o0; ((uint4*)gp)[1] = o1;
      } else { // last block = output nodes: fused sigmoid, exact f32
        float* op = out + (size_t)b * OUTSZ + li * 16;
#pragma unroll
        for (int m = 0; m < 16; m++) op[m] = fast_sigmoid(hown[m]);
      }
    } else if (k >= 1) {
      // updaters: fold src k-1 into cols k+1..32; tiles 128j x 128b, K=128
      int u = wg - NSOLVER;
      int s = k - 1, nt = (NBLK - 1 - k) * 4;
      int kb = IN_SIZE + s * NB;
      for (int idx = u; idx < nt; idx += NUPD) {
        int colb = k + 1 + (idx >> 2), bt = idx & 3;
        int jw = colb * NB + (w >> 1) * 64;
        int bw = bt * 128 + (w & 1) * 64;
        f32x4 acc[4][4];
#pragma unroll
        for (int m = 0; m < 4; m++)
#pragma unroll
          for (int n = 0; n < 4; n++) acc[m][n] = f32x4{0.f, 0.f, 0.f, 0.f};
        const float* pa[4]; const ushort* pb[4];
#pragma unroll
        for (int m = 0; m < 4; m++)
          pa[m] = W + (size_t)(jw + m * 16 + rl) * TOTAL + kb + kh * 8;
#pragma unroll
        for (int n = 0; n < 4; n++)
          pb[n] = Gt + (size_t)(bw + n * 16 + rl) * TOTAL + kb + kh * 8;
#pragma unroll
        for (int it = 0; it < 4; ++it) {
          short8 a[4], bb[4];
#pragma unroll
          for (int m = 0; m < 4; m++) a[m] = cvtA(pa[m] + it * 32);
#pragma unroll
          for (int n = 0; n < 4; n++) bb[n] = *(const short8*)(pb[n] + it * 32);
#pragma unroll
          for (int m = 0; m < 4; m++)
#pragma unroll
            for (int n = 0; n < 4; n++)
              acc[m][n] = __builtin_amdgcn_mfma_f32_16x16x32_bf16(a[m], bb[n], acc[m][n], 0, 0, 0);
        }
#pragma unroll
        for (int m = 0; m < 4; m++)
#pragma unroll
          for (int n = 0; n < 4; n++) {
            float* cp = C + (size_t)(jw + m * 16 + kh * 4) * BATCH + bw + n * 16 + rl;
#pragma unroll
            for (int q = 0; q < 4; q++) cp[(size_t)q * BATCH] += acc[m][n][q];
          }
      }
    }
    grid.sync();
  }
}

// ---------------- fallback path (round-2 proven kernels) ----------------
__global__ void conv_x(const float* __restrict__ x, ushort* __restrict__ Gt) {
  int idx = blockIdx.x * 256 + threadIdx.x;
  int b = idx >> 7, i8 = (idx & 127) * 8;
  const float* p = x + (size_t)b * IN_SIZE + i8;
  float4 v0 = *(const float4*)p, v1 = *(const float4*)(p + 4);
  uint4 o;
  o.x = pack2(v0.x, v0.y); o.y = pack2(v0.z, v0.w);
  o.z = pack2(v1.x, v1.y); o.w = pack2(v1.z, v1.w);
  *(uint4*)(Gt + (size_t)b * TOTAL + i8) = o;
}

__global__ void gemm_bf16(const float* __restrict__ W, const ushort* __restrict__ Gt,
                          float* __restrict__ C, int i0, int ilen, int j0, int init) {
  __shared__ uint4 Al[128][4];
  __shared__ uint4 Bl[128][4];
  int t = threadIdx.x;
  int jbase = j0 + blockIdx.x * 128, bbase = blockIdx.y * 128;
  int w = t >> 6, l = t & 63;
  int wm = w >> 1, wn = w & 1;
  int rl = l & 15, kh = l >> 4;
  int rdc = kh ^ ((rl >> 1) & 3);
  f32x4 acc[4][4];
#pragma unroll
  for (int m = 0; m < 4; m++)
#pragma unroll
    for (int n = 0; n < 4; n++) acc[m][n] = f32x4{0.f, 0.f, 0.f, 0.f};
  int srow = t >> 1, shalf = t & 1;
  int ssw = (srow >> 1) & 3;
  const float*  wa = W  + (size_t)(jbase + srow) * TOTAL + i0 + shalf * 16;
  const ushort* gb = Gt + (size_t)(bbase + srow) * TOTAL + i0 + shalf * 16;
  for (int kk = 0; kk < ilen; kk += 32) {
    __syncthreads();
    {
      const float* p = wa + kk;
      float4 v0 = *(const float4*)p, v1 = *(const float4*)(p + 4);
      float4 v2 = *(const float4*)(p + 8), v3 = *(const float4*)(p + 12);
      uint4 p0, p1;
      p0.x = pack2(v0.x, v0.y); p0.y = pack2(v0.z, v0.w);
      p0.z = pack2(v1.x, v1.y); p0.w = pack2(v1.z, v1.w);
      p1.x = pack2(v2.x, v2.y); p1.y = pack2(v2.z, v2.w);
      p1.z = pack2(v3.x, v3.y); p1.w = pack2(v3.z, v3.w);
      Al[srow][(shalf * 2) ^ ssw] = p0;
      Al[srow][(shalf * 2 + 1) ^ ssw] = p1;
      const uint4* q = (const uint4*)(gb + kk);
      Bl[srow][(shalf * 2) ^ ssw] = q[0];
      Bl[srow][(shalf * 2 + 1) ^ ssw] = q[1];
    }
    __syncthreads();
    short8 af[4], bf[4];
#pragma unroll
    for (int m = 0; m < 4; m++) af[m] = *(const short8*)&Al[wm * 64 + m * 16 + rl][rdc];
#pragma unroll
    for (int n = 0; n < 4; n++) bf[n] = *(const short8*)&Bl[wn * 64 + n * 16 + rl][rdc];
#pragma unroll
    for (int m = 0; m < 4; m++)
#pragma unroll
      for (int n = 0; n < 4; n++)
        acc[m][n] = __builtin_amdgcn_mfma_f32_16x16x32_bf16(af[m], bf[n], acc[m][n], 0, 0, 0);
  }
#pragma unroll
  for (int m = 0; m < 4; m++) {
    int jr = jbase + wm * 64 + m * 16 + kh * 4;
#pragma unroll
    for (int n = 0; n < 4; n++) {
      int bc = bbase + wn * 64 + n * 16 + rl;
      float* cp = C + (size_t)jr * BATCH + bc;
#pragma unroll
      for (int q = 0; q < 4; q++) {
        float* pp = cp + (size_t)q * BATCH;
        if (init) *pp = acc[m][n][q];
        else      *pp += acc[m][n][q];
      }
    }
  }
}

__global__ void solve_block_fb(const float* __restrict__ W, ushort* __restrict__ Gt,
                               const float* __restrict__ C, float* __restrict__ out,
                               int kblk) {
  __shared__ float Wt[NB][NB];
  int j0 = kblk * NB;
  int t = threadIdx.x;
  int l = t & 7, g = t >> 3;
  int b = blockIdx.x * 32 + g;
  {
    int j = t & 127, half = t >> 7;
    int pj = j ^ (((j >> 5) & 3) << 2);
    const float* wr = W + (size_t)(j0 + j) * TOTAL + IN_SIZE + j0 + half * 64;
#pragma unroll
    for (int q = 0; q < 64; q += 4) {
      float4 v = *(const float4*)(wr + q);
      int i = half * 64 + q;
      Wt[i + 0][pj] = v.x; Wt[i + 1][pj] = v.y; Wt[i + 2][pj] = v.z; Wt[i + 3][pj] = v.w;
    }
  }
  __syncthreads();
  float acc[16], hown[16];
  {
    const float* cb = C + (size_t)(j0 + l * 16) * BATCH + b;
#pragma unroll
    for (int m = 0; m < 16; m++) acc[m] = cb[(size_t)m * BATCH];
  }
  for (int r = 0; r < 8; r++) {
#pragma unroll
    for (int jj = 0; jj < 16; jj++) {
      int i = r * 16 + jj;
      float s = __shfl(acc[jj], r, 8);
      float h = fast_tanh(s);
      if (l == r) hown[jj] = h;
      const float* wrow = &Wt[i][0];
#pragma unroll
      for (int c = 0; c < 4; c++) {
        int col = l * 16 + c * 4;
        int pc = col ^ (((col >> 5) & 3) << 2);
        float4 wv = *(const float4*)(wrow + pc);
        acc[c * 4 + 0] += h * wv.x;
        acc[c * 4 + 1] += h * wv.y;
        acc[c * 4 + 2] += h * wv.z;
        acc[c * 4 + 3] += h * wv.w;
      }
    }
  }
  if (kblk < NBLK - 1) {
    ushort* gp = Gt + (size_t)b * TOTAL + IN_SIZE + j0 + l * 16;
    uint4 o0, o1;
    o0.x = pack2(hown[0],  hown[1]);  o0.y = pack2(hown[2],  hown[3]);
    o0.z = pack2(hown[4],  hown[5]);  o0.w = pack2(hown[6],  hown[7]);
    o1.x = pack2(hown[8],  hown[9]);  o1.y = pack2(hown[10], hown[11]);
    o1.z = pack2(hown[12], hown[13]); o1.w = pack2(hown[14], hown[15]);
    ((uint4*)gp)[0] = o0; ((uint4*)gp)[1] = o1;
  } else {
    float* op = out + (size_t)b * OUTSZ + l * 16;
#pragma unroll
    for (int m = 0; m < 16; m++) op[m] = fast_sigmoid(hown[m]);
  }
}

extern "C" void kernel_launch(void* const* d_in, const int* in_sizes, int n_in,
                              void* d_out, int out_size, void* d_ws, size_t ws_size,
                              hipStream_t stream) {
  const float* x = (const float*)d_in[0];
  const float* W = (const float*)d_in[1];
  float* out = (float*)d_out;
  ushort* Gt = (ushort*)d_ws;                                        // 5.4 MB
  float* C   = (float*)((char*)d_ws + (size_t)BATCH * TOTAL * 2);    // 8.7 MB

  void* args[] = {(void*)&W, (void*)&x, (void*)&Gt, (void*)&C, (void*)&out};
  hipError_t e = hipLaunchCooperativeKernel((const void*)mega, dim3(NWG), dim3(256),
                                            args, 0, stream);
  if (e != hipSuccess) {
    // fallback: proven multi-launch schedule
    hipLaunchKernelGGL(conv_x, dim3(256), dim3(256), 0, stream, x, Gt);
    hipLaunchKernelGGL(gemm_bf16, dim3(NBLK, 4), dim3(256), 0, stream,
                       W, Gt, C, 0, IN_SIZE, 0, 1);
    for (int k = 0; k < NBLK; k++) {
      hipLaunchKernelGGL(solve_block_fb, dim3(16), dim3(256), 0, stream, W, Gt, C, out, k);
      if (k < NBLK - 1)
        hipLaunchKernelGGL(gemm_bf16, dim3(NBLK - 1 - k, 4), dim3(256), 0, stream,
                           W, Gt, C, IN_SIZE + k * NB, NB, (k + 1) * NB, 0);
    }
  }
}

// Round 4
// 1519.120 us; speedup vs baseline: 1.2280x; 1.2280x over previous
//
#include <hip/hip_runtime.h>
#include <hip/hip_bf16.h>

// Problem constants (DAG_61246233641129)
#define IN_SIZE 1024
#define N_NODES 4224
#define TOTAL   5248   // IN_SIZE + N_NODES
#define BATCH   512
#define OUTSZ   128
#define NB      128    // node block size
#define NBLK    33     // N_NODES / NB

typedef __attribute__((ext_vector_type(8))) short short8;
typedef __attribute__((ext_vector_type(4))) float f32x4;

#define MFMA16 __builtin_amdgcn_mfma_f32_16x16x32_bf16

// fast tanh: tanh(x) = 1 - 2/(exp2(2x*log2e)+1)
__device__ __forceinline__ float fast_tanh(float x) {
  float e = __builtin_amdgcn_exp2f(x * 2.885390081777927f);
  return 1.0f - 2.0f * __builtin_amdgcn_rcpf(e + 1.0f);
}
__device__ __forceinline__ float fast_sigmoid(float x) {
  return __builtin_amdgcn_rcpf(1.0f + __builtin_amdgcn_exp2f(-x * 1.4426950408889634f));
}
__device__ __forceinline__ unsigned pack2(float a, float b) {
  __hip_bfloat162 h = __float22bfloat162_rn(float2{a, b});
  return *reinterpret_cast<unsigned*>(&h);
}
// load 8 contiguous f32, convert -> bf16x8 MFMA fragment
__device__ __forceinline__ short8 cvtA(const float* p) {
  float4 v0 = *(const float4*)p;
  float4 v1 = *(const float4*)(p + 4);
  union { uint4 u; short8 s; } c;
  c.u.x = pack2(v0.x, v0.y); c.u.y = pack2(v0.z, v0.w);
  c.u.z = pack2(v1.x, v1.y); c.u.w = pack2(v1.z, v1.w);
  return c.s;
}
// A-operand: row of the recurrent weight block at recurrent-offset koff.
// WB=true: preconverted bf16 Wb[j][i2]; else convert from f32 W on the fly.
template<bool WB>
__device__ __forceinline__ short8 loadA(const float* W, const ushort* Wb,
                                        int row, int koff) {
  if constexpr (WB) return *(const short8*)(Wb + (size_t)row * N_NODES + koff);
  else return cvtA(W + (size_t)row * TOTAL + IN_SIZE + koff);
}
// B-operand from swizzled LDS h buffer: batch row b, logical 16B chunk cl.
__device__ __forceinline__ short8 ldsB(const ushort* hb, int b, int cl) {
  return *(const short8*)(hb + b * NB + ((cl ^ (b & 7)) << 3));
}

// ---------------- Gt[b][i] = bf16(x[b][i]), stride IN_SIZE ----------------
__global__ void conv_x(const float* __restrict__ x, ushort* __restrict__ Gt) {
  int idx = blockIdx.x * 256 + threadIdx.x; // 65536 threads, 8 elems each
  int b = idx >> 7, i8 = (idx & 127) * 8;
  const float* p = x + (size_t)b * IN_SIZE + i8;
  float4 v0 = *(const float4*)p, v1 = *(const float4*)(p + 4);
  uint4 o;
  o.x = pack2(v0.x, v0.y); o.y = pack2(v0.z, v0.w);
  o.z = pack2(v1.x, v1.y); o.w = pack2(v1.z, v1.w);
  *(uint4*)(Gt + (size_t)b * IN_SIZE + i8) = o;
}

// -------- Wb[j][i2] = bf16(W[j][IN_SIZE+i2]) for i2 < (j/128)*128 --------
__global__ void wconv(const float* __restrict__ W, ushort* __restrict__ Wb) {
  int j = blockIdx.x;
  int lim = (j >> 7) << 7;            // only source blocks strictly before j's block
  const float* src = W + (size_t)j * TOTAL + IN_SIZE;
  ushort* dst = Wb + (size_t)j * N_NODES;
  for (int i8 = threadIdx.x * 8; i8 < lim; i8 += 256 * 8) {
    float4 v0 = *(const float4*)(src + i8);
    float4 v1 = *(const float4*)(src + i8 + 4);
    uint4 o;
    o.x = pack2(v0.x, v0.y); o.y = pack2(v0.z, v0.w);
    o.z = pack2(v1.x, v1.y); o.w = pack2(v1.z, v1.w);
    *(uint4*)(dst + i8) = o;
  }
}

// -------- init GEMM: C[j][b] = sum_i W[j][i]*Gt[b][i], i<IN_SIZE (proven) --------
__global__ void gemm_init(const float* __restrict__ W, const ushort* __restrict__ Gt,
                          float* __restrict__ C) {
  __shared__ uint4 Al[128][4];
  __shared__ uint4 Bl[128][4];
  int t = threadIdx.x;
  int jbase = blockIdx.x * 128, bbase = blockIdx.y * 128;
  int w = t >> 6, l = t & 63;
  int wm = w >> 1, wn = w & 1;
  int rl = l & 15, kh = l >> 4;
  int rdc = kh ^ ((rl >> 1) & 3);
  f32x4 acc[4][4];
#pragma unroll
  for (int m = 0; m < 4; m++)
#pragma unroll
    for (int n = 0; n < 4; n++) acc[m][n] = f32x4{0.f, 0.f, 0.f, 0.f};
  int srow = t >> 1, shalf = t & 1;
  int ssw = (srow >> 1) & 3;
  const float*  wa = W  + (size_t)(jbase + srow) * TOTAL + shalf * 16;
  const ushort* gb = Gt + (size_t)(bbase + srow) * IN_SIZE + shalf * 16;
  for (int kk = 0; kk < IN_SIZE; kk += 32) {
    __syncthreads();
    {
      const float* p = wa + kk;
      float4 v0 = *(const float4*)p, v1 = *(const float4*)(p + 4);
      float4 v2 = *(const float4*)(p + 8), v3 = *(const float4*)(p + 12);
      uint4 p0, p1;
      p0.x = pack2(v0.x, v0.y); p0.y = pack2(v0.z, v0.w);
      p0.z = pack2(v1.x, v1.y); p0.w = pack2(v1.z, v1.w);
      p1.x = pack2(v2.x, v2.y); p1.y = pack2(v2.z, v2.w);
      p1.z = pack2(v3.x, v3.y); p1.w = pack2(v3.z, v3.w);
      Al[srow][(shalf * 2) ^ ssw] = p0;
      Al[srow][(shalf * 2 + 1) ^ ssw] = p1;
      const uint4* q = (const uint4*)(gb + kk);
      Bl[srow][(shalf * 2) ^ ssw] = q[0];
      Bl[srow][(shalf * 2 + 1) ^ ssw] = q[1];
    }
    __syncthreads();
    short8 af[4], bf[4];
#pragma unroll
    for (int m = 0; m < 4; m++) af[m] = *(const short8*)&Al[wm * 64 + m * 16 + rl][rdc];
#pragma unroll
    for (int n = 0; n < 4; n++) bf[n] = *(const short8*)&Bl[wn * 64 + n * 16 + rl][rdc];
#pragma unroll
    for (int m = 0; m < 4; m++)
#pragma unroll
      for (int n = 0; n < 4; n++)
        acc[m][n] = MFMA16(af[m], bf[n], acc[m][n], 0, 0, 0);
  }
#pragma unroll
  for (int m = 0; m < 4; m++) {
    int jr = jbase + wm * 64 + m * 16 + kh * 4;
#pragma unroll
    for (int n = 0; n < 4; n++) {
      int bc = bbase + wn * 64 + n * 16 + rl;
      float* cp = C + (size_t)jr * BATCH + bc;
#pragma unroll
      for (int q = 0; q < 4; q++) cp[(size_t)q * BATCH] = acc[m][n][q];
    }
  }
}

// ---------------- persistent per-batch-group solver ----------------
// 16 WGs x 1024 threads; WG wg owns batches [wg*32, wg*32+32). No inter-WG sync.
// Per step k: phase A {waves 0-7 stage diag Wt; waves 8-15 load C col k and
// MFMA-fold h_{k-1} into LDS Cl}; sync; phase B {waves 0-3 serial-solve block k
// (setprio 1); waves 4-15 MFMA-fold h_{k-1} into C cols k+1..32}; sync.
// h lives only in double-buffered swizzled LDS (Hl) — never goes to HBM.
template<bool WB>
__global__ void __launch_bounds__(1024, 4)
persist(const float* __restrict__ W, const ushort* __restrict__ Wb,
        float* __restrict__ C, float* __restrict__ out) {
  __shared__ float Wt[NB][NB];                 // 64 KB diag block (f32, exact)
  __shared__ float Cl[NB][33];                 // 16.5 KB col-k pre-activations
  __shared__ alignas(16) ushort Hl[2][32 * NB];// 16 KB swizzled h (bf16), dbuf
  const int t = threadIdx.x;
  const int wave = t >> 6, l = t & 63, rl = l & 15, kh = l >> 4;
  const int b0 = blockIdx.x * 32;

  for (int k = 0; k < NBLK; ++k) {
    const int j0 = k * NB;
    // ---------- phase A ----------
    if (wave < 8) { // stage Wt[i][swz(j)] = W[j0+j][IN+j0+i]
      int j = t & 127, q = t >> 7; // q in 0..3
      int pj = j ^ (((j >> 5) & 3) << 2);
      const float* wr = W + (size_t)(j0 + j) * TOTAL + IN_SIZE + j0 + q * 32;
#pragma unroll
      for (int s = 0; s < 32; s += 4) {
        float4 v = *(const float4*)(wr + s);
        int i = q * 32 + s;
        Wt[i + 0][pj] = v.x; Wt[i + 1][pj] = v.y;
        Wt[i + 2][pj] = v.z; Wt[i + 3][pj] = v.w;
      }
    } else { // load C col k (+ fold src k-1) -> Cl
      int m = wave - 8;
      f32x4 a0, a1;
      const float* cp = C + (size_t)(j0 + m * 16 + kh * 4) * BATCH + b0 + rl;
#pragma unroll
      for (int q = 0; q < 4; q++) {
        a0[q] = cp[(size_t)q * BATCH];
        a1[q] = cp[(size_t)q * BATCH + 16];
      }
      if (k > 0) {
        const ushort* hb = Hl[(k - 1) & 1];
        int row = j0 + m * 16 + rl, koff = (k - 1) * NB + kh * 8;
#pragma unroll
        for (int it = 0; it < 4; ++it) {
          short8 av = loadA<WB>(W, Wb, row, koff + it * 32);
          a0 = MFMA16(av, ldsB(hb, rl, it * 4 + kh), a0, 0, 0, 0);
          a1 = MFMA16(av, ldsB(hb, 16 + rl, it * 4 + kh), a1, 0, 0, 0);
        }
      }
#pragma unroll
      for (int q = 0; q < 4; q++) {
        Cl[m * 16 + kh * 4 + q][rl] = a0[q];
        Cl[m * 16 + kh * 4 + q][16 + rl] = a1[q];
      }
    }
    __syncthreads();
    // ---------- phase B ----------
    if (wave < 4) { // serial solve, 8 lanes per batch
      __builtin_amdgcn_s_setprio(1);
      int li = t & 7, g = t >> 3, b = b0 + g;
      float acc[16], hown[16];
#pragma unroll
      for (int m = 0; m < 16; m++) acc[m] = Cl[li * 16 + m][g];
      for (int r = 0; r < 8; r++) {
#pragma unroll
        for (int jj = 0; jj < 16; jj++) {
          int i = r * 16 + jj;
          float s = __shfl(acc[jj], r, 8);
          float h = fast_tanh(s);
          if (li == r) hown[jj] = h;
          const float* wrow = &Wt[i][0];
#pragma unroll
          for (int c = 0; c < 4; c++) {
            int col = li * 16 + c * 4;
            int pc = col ^ (((col >> 5) & 3) << 2);
            float4 wv = *(const float4*)(wrow + pc);
            acc[c * 4 + 0] += h * wv.x;
            acc[c * 4 + 1] += h * wv.y;
            acc[c * 4 + 2] += h * wv.z;
            acc[c * 4 + 3] += h * wv.w;
          }
        }
      }
      __builtin_amdgcn_s_setprio(0);
      if (k < NBLK - 1) { // publish h into swizzled LDS (bf16)
        ushort* hp = Hl[k & 1] + g * NB;
        uint4 o0, o1;
        o0.x = pack2(hown[0],  hown[1]);  o0.y = pack2(hown[2],  hown[3]);
        o0.z = pack2(hown[4],  hown[5]);  o0.w = pack2(hown[6],  hown[7]);
        o1.x = pack2(hown[8],  hown[9]);  o1.y = pack2(hown[10], hown[11]);
        o1.z = pack2(hown[12], hown[13]); o1.w = pack2(hown[14], hown[15]);
        *(uint4*)(hp + (((li * 2) ^ (g & 7)) << 3))     = o0;
        *(uint4*)(hp + (((li * 2 + 1) ^ (g & 7)) << 3)) = o1;
      } else { // output nodes: fused sigmoid, f32
        float* op = out + (size_t)b * OUTSZ + li * 16;
#pragma unroll
        for (int m = 0; m < 16; m++) op[m] = fast_sigmoid(hown[m]);
      }
    } else if (k > 0 && k < NBLK - 1) { // fold src k-1 into future cols
      const ushort* hb = Hl[(k - 1) & 1];
      int fw = wave - 4;
      int ncols = NBLK - 1 - k;
      for (int c = fw; c < ncols; c += 12) {
        int jb = (k + 1 + c) * NB;
        int koff = (k - 1) * NB + kh * 8;
#pragma unroll
        for (int m = 0; m < 8; ++m) {
          int row = jb + m * 16 + rl;
          float* cp = C + (size_t)(jb + m * 16 + kh * 4) * BATCH + b0 + rl;
          f32x4 a0, a1;
#pragma unroll
          for (int q = 0; q < 4; q++) {
            a0[q] = cp[(size_t)q * BATCH];
            a1[q] = cp[(size_t)q * BATCH + 16];
          }
#pragma unroll
          for (int it = 0; it < 4; ++it) {
            short8 av = loadA<WB>(W, Wb, row, koff + it * 32);
            a0 = MFMA16(av, ldsB(hb, rl, it * 4 + kh), a0, 0, 0, 0);
            a1 = MFMA16(av, ldsB(hb, 16 + rl, it * 4 + kh), a1, 0, 0, 0);
          }
#pragma unroll
          for (int q = 0; q < 4; q++) {
            cp[(size_t)q * BATCH] = a0[q];
            cp[(size_t)q * BATCH + 16] = a1[q];
          }
        }
      }
    }
    __syncthreads();
  }
}

extern "C" void kernel_launch(void* const* d_in, const int* in_sizes, int n_in,
                              void* d_out, int out_size, void* d_ws, size_t ws_size,
                              hipStream_t stream) {
  const float* x = (const float*)d_in[0];
  const float* W = (const float*)d_in[1];
  float* out = (float*)d_out;

  // ws carve: Gt bf16 [512][1024] (1 MB) | C f32 [4224][512] (8.65 MB) | Wb bf16 [4224][4224] (35.7 MB)
  ushort* Gt = (ushort*)d_ws;
  float*  C  = (float*)((char*)d_ws + (size_t)BATCH * IN_SIZE * sizeof(ushort));
  ushort* Wb = (ushort*)((char*)C + (size_t)N_NODES * BATCH * sizeof(float));
  size_t need = (size_t)BATCH * IN_SIZE * 2 + (size_t)N_NODES * BATCH * 4 +
                (size_t)N_NODES * N_NODES * 2;
  bool use_wb = ws_size >= need;

  hipLaunchKernelGGL(conv_x, dim3(256), dim3(256), 0, stream, x, Gt);
  if (use_wb)
    hipLaunchKernelGGL(wconv, dim3(N_NODES), dim3(256), 0, stream, W, Wb);
  hipLaunchKernelGGL(gemm_init, dim3(NBLK, 4), dim3(256), 0, stream, W, Gt, C);
  if (use_wb)
    hipLaunchKernelGGL((persist<true>), dim3(16), dim3(1024), 0, stream, W, Wb, C, out);
  else
    hipLaunchKernelGGL((persist<false>), dim3(16), dim3(1024), 0, stream, W, Wb, C, out);
}

// Round 5
// 778.642 us; speedup vs baseline: 2.3957x; 1.9510x over previous
//
#include <hip/hip_runtime.h>
#include <hip/hip_bf16.h>

// Problem constants (DAG_61246233641129)
#define IN_SIZE 1024
#define N_NODES 4224
#define TOTAL   5248   // IN_SIZE + N_NODES
#define BATCH   512
#define OUTSZ   128
#define NB      128    // node block size
#define NBLK    33     // N_NODES / NB
#define NSOLVE  16     // solver WGs (32 batches each)
#define NOWN    124    // fold owners: (c,q), c=2..32, q=0..3
#define NINITX  8      // init-only units: c=0,1
#define NWGS    (NSOLVE + NOWN + NINITX)  // 148

typedef __attribute__((ext_vector_type(8))) short short8;
typedef __attribute__((ext_vector_type(4))) float f32x4;

#define MFMA16 __builtin_amdgcn_mfma_f32_16x16x32_bf16
#define AQ __ATOMIC_ACQUIRE
#define RL __ATOMIC_RELEASE
#define AG __HIP_MEMORY_SCOPE_AGENT

// fast tanh: tanh(x) = 1 - 2/(exp2(2x*log2e)+1)
__device__ __forceinline__ float fast_tanh(float x) {
  float e = __builtin_amdgcn_exp2f(x * 2.885390081777927f);
  return 1.0f - 2.0f * __builtin_amdgcn_rcpf(e + 1.0f);
}
__device__ __forceinline__ float fast_sigmoid(float x) {
  return __builtin_amdgcn_rcpf(1.0f + __builtin_amdgcn_exp2f(-x * 1.4426950408889634f));
}
__device__ __forceinline__ unsigned pack2(float a, float b) {
  __hip_bfloat162 h = __float22bfloat162_rn(float2{a, b});
  return *reinterpret_cast<unsigned*>(&h);
}
// load 8 contiguous f32 -> 8 bf16 (16 B)
__device__ __forceinline__ uint4 cvtA_u4(const float* p) {
  float4 v0 = *(const float4*)p;
  float4 v1 = *(const float4*)(p + 4);
  uint4 u;
  u.x = pack2(v0.x, v0.y); u.y = pack2(v0.z, v0.w);
  u.z = pack2(v1.x, v1.y); u.w = pack2(v1.z, v1.w);
  return u;
}
__device__ __forceinline__ short8 cvtA(const float* p) {
  union { uint4 u; short8 s; } c; c.u = cvtA_u4(p); return c.s;
}
// A-operand row fragment of recurrent weights at recurrent offset koff
template<bool WB>
__device__ __forceinline__ short8 loadA(const float* W, const ushort* Wb,
                                        int row, int koff) {
  if constexpr (WB) return *(const short8*)(Wb + (size_t)row * N_NODES + koff);
  else return cvtA(W + (size_t)row * TOTAL + IN_SIZE + koff);
}
// B-operand from swizzled LDS h buffer: local batch b (0..31), logical chunk cl (0..15)
__device__ __forceinline__ short8 ldsB(const ushort* hb, int b, int cl) {
  return *(const short8*)(hb + b * NB + ((cl ^ (b & 7)) << 3));
}

// ---- LDS image (98816 B > 80 KB -> exactly 1 WG/CU) ----
struct SolverSM {
  float Wt[NB][NB];          // 64 KB diag block, transposed+swizzled (f32 exact)
  float Cl[NB][33];          // 16.9 KB col-k pre-activations [node][batch]
  ushort Hl[2][32 * NB];     // 16 KB swizzled h (bf16), double-buffered
};
struct UpdSM {
  uint4 Al[128][4];          // 8 KB A tile (bf16, swizzled 16B chunks)
  uint4 Bl[128][4];          // 8 KB B tile
};
union MegaSM { SolverSM s; UpdSM u; };

// ---------------- prep: zero flags ----------------
__global__ void zero_fl(int* fl) { if (threadIdx.x < 128) fl[threadIdx.x] = 0; }

// ---- prep: Wd[k][i][swz(j)] = W[k*NB+j][IN+k*NB+i]  (solve-ready diag image) ----
__global__ void wdiag(const float* __restrict__ W, float* __restrict__ Wd) {
  __shared__ float tl[32][33];
  int k = blockIdx.x;
  int ti = blockIdx.y & 3, tj = blockIdx.y >> 2;  // 32-wide i/j tiles
  int tx = threadIdx.x & 31, ty = threadIdx.x >> 5;
  int j0 = k * NB;
#pragma unroll
  for (int q = 0; q < 4; q++) {
    int jl = ty + q * 8;
    tl[jl][tx] = W[(size_t)(j0 + tj * 32 + jl) * TOTAL + IN_SIZE + j0 + ti * 32 + tx];
  }
  __syncthreads();
  int swz = (tj & 3) << 2;
#pragma unroll
  for (int q = 0; q < 4; q++) {
    int il = ty + q * 8;
    Wd[(size_t)k * NB * NB + (ti * 32 + il) * NB + ((tj * 32 + tx) ^ swz)] = tl[tx][il];
  }
}

// ---- prep: Wb[j][i2] = bf16(W[j][IN+i2]) for i2 < (j/128)*128 ----
__global__ void wconv(const float* __restrict__ W, ushort* __restrict__ Wb) {
  int j = blockIdx.x;
  int lim = (j >> 7) << 7;
  const float* src = W + (size_t)j * TOTAL + IN_SIZE;
  ushort* dst = Wb + (size_t)j * N_NODES;
  for (int i8 = threadIdx.x * 8; i8 < lim; i8 += 256 * 8)
    *(uint4*)(dst + i8) = cvtA_u4(src + i8);
}

// ---- 128x128 GEMM tile: INIT (K=1024 from W,x f32) or FOLD (K=128 from Wb/W + Hg[s]) ----
template<bool WB, bool INIT>
__device__ void do_tile(UpdSM& u, const float* W, const ushort* Wb,
                        const ushort* Hg, const float* x, float* C,
                        int c, int q, int s, int t) {
  const int w = t >> 6, l = t & 63, rl = l & 15, kh = l >> 4;
  const int wm = w >> 1, wn = w & 1;                 // 4 j-strips x 2 b-halves
  const int jbase = c * NB, bbase = q * 128;
  const int srow = t & 127, sch = t >> 7;            // staging row / 16B chunk
  const int ssw = (srow >> 1) & 3;
  const int rdc = kh ^ ((rl >> 1) & 3);
  f32x4 acc[2][4];
#pragma unroll
  for (int m = 0; m < 2; m++)
#pragma unroll
    for (int n = 0; n < 4; n++) acc[m][n] = f32x4{0.f, 0.f, 0.f, 0.f};

  const int nk = INIT ? IN_SIZE : NB;
  for (int kk = 0; kk < nk; kk += 32) {
    uint4 av, bv;
    if constexpr (INIT) {
      av = cvtA_u4(W + (size_t)(jbase + srow) * TOTAL + kk + sch * 8);
      bv = cvtA_u4(x + (size_t)(bbase + srow) * IN_SIZE + kk + sch * 8);
    } else {
      if constexpr (WB)
        av = *(const uint4*)(Wb + (size_t)(jbase + srow) * N_NODES + s * NB + kk + sch * 8);
      else
        av = cvtA_u4(W + (size_t)(jbase + srow) * TOTAL + IN_SIZE + s * NB + kk + sch * 8);
      bv = *(const uint4*)(Hg + ((size_t)s * BATCH + bbase + srow) * NB + kk + sch * 8);
    }
    __syncthreads();
    u.Al[srow][sch ^ ssw] = av;
    u.Bl[srow][sch ^ ssw] = bv;
    __syncthreads();
    short8 af[2], bf[4];
#pragma unroll
    for (int m = 0; m < 2; m++)
      af[m] = *(const short8*)&u.Al[wm * 32 + m * 16 + rl][rdc];
#pragma unroll
    for (int n = 0; n < 4; n++)
      bf[n] = *(const short8*)&u.Bl[wn * 64 + n * 16 + rl][rdc];
#pragma unroll
    for (int m = 0; m < 2; m++)
#pragma unroll
      for (int n = 0; n < 4; n++)
        acc[m][n] = MFMA16(af[m], bf[n], acc[m][n], 0, 0, 0);
  }
#pragma unroll
  for (int m = 0; m < 2; m++)
#pragma unroll
    for (int n = 0; n < 4; n++) {
      float* cp = C + (size_t)(jbase + wm * 32 + m * 16 + kh * 4) * BATCH +
                  bbase + wn * 64 + n * 16 + rl;
#pragma unroll
      for (int qq = 0; qq < 4; qq++) {
        if constexpr (INIT) cp[(size_t)qq * BATCH] = acc[m][n][qq];
        else                cp[(size_t)qq * BATCH] += acc[m][n][qq];
      }
    }
  __syncthreads();
}

// ---------------- the pipelined persistent kernel ----------------
// fl[0..32]  = colcnt[c]: completed (c,q) units (init counts 1, each fold counts 1)
// fl[64..95] = hflag[s]:  solver WGs that published h_s (target 16)
template<bool WB>
__global__ void __launch_bounds__(512, 1)
persist(const float* __restrict__ W, const ushort* __restrict__ Wb,
        const float* __restrict__ Wd, ushort* __restrict__ Hg,
        float* __restrict__ C, const float* __restrict__ x,
        float* __restrict__ out, int* __restrict__ fl) {
  __shared__ MegaSM sm;
  const int wg = blockIdx.x, t = threadIdx.x;

  if (wg >= NSOLVE) {
    // ---------------- updaters ----------------
    int u = wg - NSOLVE;
    bool owner = (u < NOWN);
    int c, q;
    if (owner) { c = 2 + (u >> 2); q = u & 3; }
    else       { int v = u - NOWN; c = v >> 2; q = v & 3; }
    // init unit: C[c-tile][q-quad] = W[:, :1024] . x^T
    do_tile<WB, true>(sm.u, W, Wb, Hg, x, C, c, q, 0, t);
    if (t == 0) { __threadfence(); __hip_atomic_fetch_add(&fl[c], 1, RL, AG); }
    if (owner) {
      for (int s = 0; s + 2 <= c; ++s) {
        if (t == 0)
          while (__hip_atomic_load(&fl[64 + s], AQ, AG) < NSOLVE)
            __builtin_amdgcn_s_sleep(4);
        __syncthreads();
        do_tile<WB, false>(sm.u, W, Wb, Hg, x, C, c, q, s, t);
        if (t == 0) { __threadfence(); __hip_atomic_fetch_add(&fl[c], 1, RL, AG); }
      }
    }
    return;
  }

  // ---------------- solver (wg 0..15, batches [wg*32, wg*32+32)) ----------------
  const int wave = t >> 6, l = t & 63, rl = l & 15, kh = l >> 4;
  const int b0 = wg * 32;
  // prologue: Wt <- Wd[0] (flat 64 KB coalesced copy)
#pragma unroll
  for (int q = 0; q < 8; q++) {
    int i = q * 512 + t;
    ((f32x4*)sm.s.Wt)[i] = ((const f32x4*)Wd)[i];
  }
  f32x4 pf[16]; // next-diag-block register prefetch (waves 4-7)

  for (int k = 0; k < NBLK; ++k) {
    // gate: all (k,q) units done (init + folds of sources 0..k-2)
    if (t == 0) {
      int tgt = (k == 0) ? 4 : 4 * k;
      while (__hip_atomic_load(&fl[k], AQ, AG) < tgt) __builtin_amdgcn_s_sleep(1);
    }
    __syncthreads();

    // phase A: read C col k + fold h_{k-1} -> col k (8 waves, 16-j strips)
    {
      const int jr = k * NB + wave * 16;
      f32x4 a0, a1;
      const float* cp = C + (size_t)(jr + kh * 4) * BATCH + b0 + rl;
#pragma unroll
      for (int qq = 0; qq < 4; qq++) {
        a0[qq] = cp[(size_t)qq * BATCH];
        a1[qq] = cp[(size_t)qq * BATCH + 16];
      }
      if (k > 0) {
        const ushort* hb = sm.s.Hl[(k - 1) & 1];
        const int arow = jr + rl;
        const int koff = (k - 1) * NB + kh * 8;
#pragma unroll
        for (int it = 0; it < 4; ++it) {
          short8 av = loadA<WB>(W, Wb, arow, koff + it * 32);
          a0 = MFMA16(av, ldsB(hb, rl, it * 4 + kh), a0, 0, 0, 0);
          a1 = MFMA16(av, ldsB(hb, 16 + rl, it * 4 + kh), a1, 0, 0, 0);
        }
      }
#pragma unroll
      for (int qq = 0; qq < 4; qq++) {
        sm.s.Cl[wave * 16 + kh * 4 + qq][rl] = a0[qq];
        sm.s.Cl[wave * 16 + kh * 4 + qq][16 + rl] = a1[qq];
      }
    }
    __syncthreads();

    // phase B: waves 0-3 serial-solve; waves 4-7 prefetch next diag block to regs
    float hown[16];
    if (wave < 4) {
      __builtin_amdgcn_s_setprio(1);
      int li = t & 7, g = t >> 3;
      float acc[16];
#pragma unroll
      for (int m = 0; m < 16; m++) acc[m] = sm.s.Cl[li * 16 + m][g];
      for (int r = 0; r < 8; r++) {
#pragma unroll
        for (int jj = 0; jj < 16; jj++) {
          int i = r * 16 + jj;
          float sv = __shfl(acc[jj], r, 8);
          float h = fast_tanh(sv);
          if (li == r) hown[jj] = h;
          const float* wrow = &sm.s.Wt[i][0];
#pragma unroll
          for (int cc = 0; cc < 4; cc++) {
            int col = li * 16 + cc * 4;
            int pc = col ^ (((col >> 5) & 3) << 2);
            float4 wv = *(const float4*)(wrow + pc);
            acc[cc * 4 + 0] += h * wv.x;
            acc[cc * 4 + 1] += h * wv.y;
            acc[cc * 4 + 2] += h * wv.z;
            acc[cc * 4 + 3] += h * wv.w;
          }
        }
      }
      __builtin_amdgcn_s_setprio(0);
    } else if (k < NBLK - 1) {
      const f32x4* src = (const f32x4*)(Wd + (size_t)(k + 1) * NB * NB);
      int base = t - 256;
#pragma unroll
      for (int q = 0; q < 16; q++) pf[q] = src[q * 256 + base];
    }
    __syncthreads();

    // phase C: publish h; waves 4-7 install prefetched diag block
    if (wave < 4) {
      int li = t & 7, g = t >> 3, b = b0 + g;
      if (k < NBLK - 1) {
        uint4 o0, o1;
        o0.x = pack2(hown[0],  hown[1]);  o0.y = pack2(hown[2],  hown[3]);
        o0.z = pack2(hown[4],  hown[5]);  o0.w = pack2(hown[6],  hown[7]);
        o1.x = pack2(hown[8],  hown[9]);  o1.y = pack2(hown[10], hown[11]);
        o1.z = pack2(hown[12], hown[13]); o1.w = pack2(hown[14], hown[15]);
        ushort* hp = sm.s.Hl[k & 1] + g * NB;          // LDS (own next fold)
        *(uint4*)(hp + (((li * 2) ^ (g & 7)) << 3))     = o0;
        *(uint4*)(hp + (((li * 2 + 1) ^ (g & 7)) << 3)) = o1;
        if (k <= 30) {                                  // global (for owners)
          ushort* gp = Hg + ((size_t)k * BATCH + b) * NB + li * 16;
          ((uint4*)gp)[0] = o0; ((uint4*)gp)[1] = o1;
        }
      } else {
        float* op = out + (size_t)b * OUTSZ + li * 16;
#pragma unroll
        for (int m = 0; m < 16; m++) op[m] = fast_sigmoid(hown[m]);
      }
    } else if (k < NBLK - 1) {
      int base = t - 256;
#pragma unroll
      for (int q = 0; q < 16; q++) ((f32x4*)sm.s.Wt)[q * 256 + base] = pf[q];
    }
    __syncthreads();
    if (t == 0 && k <= 30) {
      __threadfence();
      __hip_atomic_fetch_add(&fl[64 + k], 1, RL, AG);
    }
  }
}

extern "C" void kernel_launch(void* const* d_in, const int* in_sizes, int n_in,
                              void* d_out, int out_size, void* d_ws, size_t ws_size,
                              hipStream_t stream) {
  const float* x = (const float*)d_in[0];
  const float* W = (const float*)d_in[1];
  float* out = (float*)d_out;

  // ws carve
  char* p = (char*)d_ws;
  int*    fl = (int*)p;                 p += 512;
  float*  C  = (float*)p;               p += (size_t)N_NODES * BATCH * 4;   // 8.65 MB
  float*  Wd = (float*)p;               p += (size_t)NBLK * NB * NB * 4;    // 2.16 MB
  ushort* Hg = (ushort*)p;              p += (size_t)NBLK * BATCH * NB * 2; // 4.33 MB
  ushort* Wb = (ushort*)p;              // 35.7 MB (optional)
  size_t need_wb = (size_t)(p - (char*)d_ws) + (size_t)N_NODES * N_NODES * 2;
  bool use_wb = ws_size >= need_wb;

  hipLaunchKernelGGL(zero_fl, dim3(1), dim3(128), 0, stream, fl);
  hipLaunchKernelGGL(wdiag, dim3(NBLK, 16), dim3(256), 0, stream, W, Wd);
  if (use_wb) {
    hipLaunchKernelGGL(wconv, dim3(N_NODES), dim3(256), 0, stream, W, Wb);
    hipLaunchKernelGGL((persist<true>), dim3(NWGS), dim3(512), 0, stream,
                       W, Wb, Wd, Hg, C, x, out, fl);
  } else {
    hipLaunchKernelGGL((persist<false>), dim3(NWGS), dim3(512), 0, stream,
                       W, Wb, Wd, Hg, C, x, out, fl);
  }
}